// Round 3
// baseline (192.948 us; speedup 1.0000x reference)
//
#include <hip/hip_runtime.h>
#include <stdint.h>

// ---------------------------------------------------------------------------
// HeteNet round 3: NO bucketing. Every wave computes all 4 experts + critic
// for 64 consecutive tokens and selects per-token via hete_pick.
// Transposed MFMA (D = h^T): A-operand = frag-ready weights (wp), B-operand =
// x/h token-frags. Per-wave private LDS slice for the h^T -> h transpose; no
// __syncthreads anywhere. 2 kernels total: prep (weights->bf16 frags) + main.
// ws layout: wp[56320 shorts] only.
// ---------------------------------------------------------------------------

typedef float v4f __attribute__((ext_vector_type(4)));
typedef short v8s __attribute__((ext_vector_type(8)));

#define WP2_OFF 30720  // 60 frag-blocks * 512 shorts
#define WP3_OFF 51200  // + 40 * 512

static __device__ __forceinline__ short f2bf(float f) {
    union { float f; uint32_t u; } c; c.f = f;
    uint32_t u = c.u;
    uint32_t r = (u + 0x7FFFu + ((u >> 16) & 1u)) >> 16;
    return (short)r;
}
static __device__ __forceinline__ uint32_t pk2(float a, float b) {
    return (uint32_t)(uint16_t)f2bf(a) | ((uint32_t)(uint16_t)f2bf(b) << 16);
}

// ---------------- weight prep: frag-ready bf16 layout (unchanged) ----------
// frag-block = 64 lanes x 8 bf16: lane holds W[k][n], n = lane&15,
// k = (lane>>4)*8 + j.  L1 ids: (ne*3+ks)*4+nt (ne=4 critic), 60 blocks.
// L2 ids: (ne*2+ks)*4+nt, 40 blocks. L3: ne*2+ks (experts, N=16), 8..9 critic.
__global__ void prep_kernel(const float* __restrict__ W1, const float* __restrict__ cW1,
                            const float* __restrict__ W2, const float* __restrict__ cW2,
                            const float* __restrict__ W3, const float* __restrict__ cW3,
                            short* __restrict__ wp) {
    int b = blockIdx.x, lane = threadIdx.x;
    int nl = lane & 15, quad = lane >> 4;
    short frag[8];
    if (b < 60) {
        int e = b / 12, rem = b % 12, ks = rem / 4, nt = rem % 4;
        int n = nt * 16 + nl;
#pragma unroll
        for (int j = 0; j < 8; j++) {
            int k = ks * 32 + quad * 8 + j;
            float v = 0.f;
            if (k < 68) v = (e < 4) ? W1[(e * 68 + k) * 64 + n] : cW1[k * 64 + n];
            frag[j] = f2bf(v);
        }
    } else if (b < 100) {
        int u = b - 60, e = u / 8, ks = (u % 8) / 4, nt = u % 4;
        int n = nt * 16 + nl;
#pragma unroll
        for (int j = 0; j < 8; j++) {
            int k = ks * 32 + quad * 8 + j;
            frag[j] = f2bf((e < 4) ? W2[(e * 64 + k) * 64 + n] : cW2[k * 64 + n]);
        }
    } else {
        int u = b - 100;
#pragma unroll
        for (int j = 0; j < 8; j++) {
            int ks = (u < 8) ? (u & 1) : (u - 8);
            int k  = ks * 32 + quad * 8 + j;
            float v;
            if (u < 8) { int ee = u >> 1; v = W3[(ee * 64 + k) * 16 + nl]; }
            else       { v = (nl == 0) ? cW3[k] : 0.f; }
            frag[j] = f2bf(v);
        }
    }
    v8s pk = { frag[0], frag[1], frag[2], frag[3], frag[4], frag[5], frag[6], frag[7] };
    *(v8s*)(wp + (size_t)b * 512 + lane * 8) = pk;
}

// ---------------- main kernel: wave = 64 tokens, all nets, no barriers -----
// LDS h layout per wave: 64 rows (tokens) x 36 dwords (64 bf16 + 8 pad),
// 16B groups XOR-swizzled by (row&7) to spread banks.

__global__ __launch_bounds__(256, 3) void main_kernel(
    const float* __restrict__ obs, const float* __restrict__ gp,
    const int* __restrict__ hete, const short* __restrict__ wp,
    const float* __restrict__ b1, const float* __restrict__ b2, const float* __restrict__ b3,
    const float* __restrict__ cb1, const float* __restrict__ cb2, const float* __restrict__ cb3,
    float* __restrict__ out)
{
    __shared__ __align__(16) uint32_t H_[4][64 * 36];
    int tid = threadIdx.x, wv = tid >> 6, lane = tid & 63;
    int ml = lane & 15, quad = lane >> 4;
    uint32_t* H = H_[wv];
    int base = (blockIdx.x * 4 + wv) * 64;

    v8s      xf[2][4];     // x B-frags (k 0..63), held across all 5 nets
    uint32_t gpk[4][2];    // gp part of k=64..67 (quad 0 lanes only)
    int      tpv[4];       // expert pick per token-tile
    float    oE[4][4];     // selected expert logits (biased)
    float    oV[4];        // critic value (valid on quad==0)

#pragma unroll
    for (int tt = 0; tt < 4; tt++) {
        int tok = base + tt * 16 + ml;
        tpv[tt] = hete[tok];
        const float* xr = obs + (size_t)tok * 64 + quad * 8;
#pragma unroll
        for (int ks = 0; ks < 2; ks++) {
            float4 a = *(const float4*)(xr + ks * 32);
            float4 c = *(const float4*)(xr + ks * 32 + 4);
            v8s f;
            f[0] = f2bf(a.x); f[1] = f2bf(a.y); f[2] = f2bf(a.z); f[3] = f2bf(a.w);
            f[4] = f2bf(c.x); f[5] = f2bf(c.y); f[6] = f2bf(c.z); f[7] = f2bf(c.w);
            xf[ks][tt] = f;
        }
        if (quad == 0) {
            float4 g = *(const float4*)(gp + (size_t)(tok >> 7) * 4);
            gpk[tt][0] = pk2(g.x, g.y); gpk[tt][1] = pk2(g.z, g.w);
        } else { gpk[tt][0] = 0; gpk[tt][1] = 0; }
    }

    float cb3v = cb3[0];

    for (int ne = 0; ne < 5; ne++) {   // 0..3 experts, 4 = critic
        // ---- layer 1: D1[hid][token] = sum_k W1[k][hid] * x[token][k] ----
        v4f acc[4][4];
#pragma unroll
        for (int tt = 0; tt < 4; tt++)
#pragma unroll
            for (int nt = 0; nt < 4; nt++) acc[tt][nt] = (v4f){0.f, 0.f, 0.f, 0.f};
#pragma unroll
        for (int ks = 0; ks < 3; ks++) {
            v8s wa[4];
#pragma unroll
            for (int nt = 0; nt < 4; nt++)
                wa[nt] = *(const v8s*)(wp + (size_t)((ne * 3 + ks) * 4 + nt) * 512 + lane * 8);
#pragma unroll
            for (int tt = 0; tt < 4; tt++) {
                v8s xb;
                if (ks < 2) xb = xf[ks][tt];
                else {
                    union { uint32_t u[4]; v8s s; } cv;
                    cv.u[0] = gpk[tt][0]; cv.u[1] = gpk[tt][1]; cv.u[2] = 0; cv.u[3] = 0;
                    xb = cv.s;
                }
#pragma unroll
                for (int nt = 0; nt < 4; nt++)
                    acc[tt][nt] = __builtin_amdgcn_mfma_f32_16x16x32_bf16(wa[nt], xb, acc[tt][nt], 0, 0, 0);
            }
        }
        // ---- bias+relu, pack, write h1 to per-wave LDS (swizzled) ----
        const float* B1 = (ne < 4) ? (b1 + ne * 64) : cb1;
        float4 bv[4];
#pragma unroll
        for (int nt = 0; nt < 4; nt++) bv[nt] = *(const float4*)(B1 + nt * 16 + quad * 4);
#pragma unroll
        for (int tt = 0; tt < 4; tt++) {
            int tL = tt * 16 + ml, rb = tL * 36, sw = tL & 7;
#pragma unroll
            for (int nt = 0; nt < 4; nt++) {
                float v0 = fmaxf(acc[tt][nt][0] + bv[nt].x, 0.f);
                float v1 = fmaxf(acc[tt][nt][1] + bv[nt].y, 0.f);
                float v2 = fmaxf(acc[tt][nt][2] + bv[nt].z, 0.f);
                float v3 = fmaxf(acc[tt][nt][3] + bv[nt].w, 0.f);
                int g = 2 * nt + (quad >> 1);
                uint2 w2 = { pk2(v0, v1), pk2(v2, v3) };
                *(uint2*)&H[rb + ((g ^ sw) << 2) + 2 * (quad & 1)] = w2;
            }
        }
        // ---- preload L2/L3 weights + biases for this net ----
        v8s wa2[2][4];
#pragma unroll
        for (int ks2 = 0; ks2 < 2; ks2++)
#pragma unroll
            for (int nt = 0; nt < 4; nt++)
                wa2[ks2][nt] = *(const v8s*)(wp + WP2_OFF +
                    (size_t)((ne * 2 + ks2) * 4 + nt) * 512 + lane * 8);
        const float* B2 = (ne < 4) ? (b2 + ne * 64) : cb2;
        float4 bv2[4];
#pragma unroll
        for (int nt = 0; nt < 4; nt++) bv2[nt] = *(const float4*)(B2 + nt * 16 + quad * 4);
        v8s w3f[2];
#pragma unroll
        for (int ks2 = 0; ks2 < 2; ks2++)
            w3f[ks2] = *(const v8s*)(wp + WP3_OFF +
                (size_t)((ne < 4) ? (ne * 2 + ks2) : (8 + ks2)) * 512 + lane * 8);
        float4 b3v = (ne < 4) ? *(const float4*)(b3 + ne * 16 + quad * 4)
                              : (float4){0.f, 0.f, 0.f, 0.f};

        // ---- per token-tile: L2 (read h1, mfma, write h2) then L3 ----
#pragma unroll
        for (int tt = 0; tt < 4; tt++) {
            int tL = tt * 16 + ml, rb = tL * 36, sw = tL & 7;
            v4f a2[4];
#pragma unroll
            for (int nt = 0; nt < 4; nt++) a2[nt] = (v4f){0.f, 0.f, 0.f, 0.f};
#pragma unroll
            for (int ks2 = 0; ks2 < 2; ks2++) {
                v8s hf = *(const v8s*)&H[rb + (((4 * ks2 + quad) ^ sw) << 2)];
#pragma unroll
                for (int nt = 0; nt < 4; nt++)
                    a2[nt] = __builtin_amdgcn_mfma_f32_16x16x32_bf16(wa2[ks2][nt], hf, a2[nt], 0, 0, 0);
            }
#pragma unroll
            for (int nt = 0; nt < 4; nt++) {   // h2 overwrites h1 rows of this tt
                float v0 = fmaxf(a2[nt][0] + bv2[nt].x, 0.f);
                float v1 = fmaxf(a2[nt][1] + bv2[nt].y, 0.f);
                float v2 = fmaxf(a2[nt][2] + bv2[nt].z, 0.f);
                float v3 = fmaxf(a2[nt][3] + bv2[nt].w, 0.f);
                int g = 2 * nt + (quad >> 1);
                uint2 w2 = { pk2(v0, v1), pk2(v2, v3) };
                *(uint2*)&H[rb + ((g ^ sw) << 2) + 2 * (quad & 1)] = w2;
            }
            v4f a3 = (v4f){0.f, 0.f, 0.f, 0.f};
#pragma unroll
            for (int ks2 = 0; ks2 < 2; ks2++) {
                v8s hf2 = *(const v8s*)&H[rb + (((4 * ks2 + quad) ^ sw) << 2)];
                a3 = __builtin_amdgcn_mfma_f32_16x16x32_bf16(w3f[ks2], hf2, a3, 0, 0, 0);
            }
            if (ne < 4) {
#pragma unroll
                for (int rr = 0; rr < 4; rr++) {
                    float val = a3[rr] + ((const float*)&b3v)[rr];
                    if (tpv[tt] == ne) oE[tt][rr] = val;
                }
            } else {
                oV[tt] = a3[0] + cb3v;   // valid where quad==0 (hid row 0)
            }
        }
    }

    // ---- store: out[token][0..15] logits, out[token][16] value ----
#pragma unroll
    for (int tt = 0; tt < 4; tt++) {
        int tok = base + tt * 16 + ml;
        float* o = out + (size_t)tok * 17 + quad * 4;
#pragma unroll
        for (int rr = 0; rr < 4; rr++) o[rr] = oE[tt][rr];
        if (quad == 0) out[(size_t)tok * 17 + 16] = oV[tt];
    }
}

// ---------------------------------------------------------------------------

extern "C" void kernel_launch(void* const* d_in, const int* in_sizes, int n_in,
                              void* d_out, int out_size, void* d_ws, size_t ws_size,
                              hipStream_t stream) {
    const float* obs = (const float*)d_in[0];
    const int*  hete = (const int*)d_in[1];
    const float* gp  = (const float*)d_in[2];
    const float* W1  = (const float*)d_in[3];
    const float* b1  = (const float*)d_in[4];
    const float* W2  = (const float*)d_in[5];
    const float* b2  = (const float*)d_in[6];
    const float* W3  = (const float*)d_in[7];
    const float* b3  = (const float*)d_in[8];
    const float* cW1 = (const float*)d_in[9];
    const float* cb1 = (const float*)d_in[10];
    const float* cW2 = (const float*)d_in[11];
    const float* cb2 = (const float*)d_in[12];
    const float* cW3 = (const float*)d_in[13];
    const float* cb3 = (const float*)d_in[14];
    float* out = (float*)d_out;

    short* wp = (short*)d_ws;   // 56320 shorts

    prep_kernel<<<110,   64, 0, stream>>>(W1, cW1, W2, cW2, W3, cW3, wp);
    main_kernel<<<1024, 256, 0, stream>>>(obs, gp, hete, wp,
                                          b1, b2, b3, cb1, cb2, cb3, out);
}

// Round 4
// 160.844 us; speedup vs baseline: 1.1996x; 1.1996x over previous
//
#include <hip/hip_runtime.h>
#include <stdint.h>

// ---------------------------------------------------------------------------
// HeteNet round 4: no bucketing, no LDS, no barriers.
// Every wave computes all 4 experts + critic for 32 tokens (2 tiles of 16),
// selecting per-token via hete_pick. Transposed MFMA: A = frag-ready weights,
// B = token-frags. The k-ordering of W2/W3 A-fragments is permuted at prep
// time so each lane's MFMA D-registers ARE the next layer's B-frag contents:
//   k-slot (ks2, quad, j)  <->  hid = (2*ks2 + (j>>2))*16 + quad*4 + (j&3)
// so layer transitions are pure in-lane register repacking (relu + bf16 pack).
// Biases: b1 folded into K-slot 68 (x[68]=1), b2/b3 folded into acc-init.
// ws layout: wp[56320 shorts] only.
// ---------------------------------------------------------------------------

typedef float v4f __attribute__((ext_vector_type(4)));
typedef short v8s __attribute__((ext_vector_type(8)));

#define WP2_OFF 30720  // 60 frag-blocks * 512 shorts
#define WP3_OFF 51200  // + 40 * 512

// round-to-nearest-away bf16 (ties differ from RNE only in direction, same
// 0.5-ulp magnitude -> absmax unchanged; 3 VALU ops per pair vs ~10 for RNE)
static __device__ __forceinline__ uint32_t rna_hi(float f) {
    union { float f; uint32_t u; } c; c.f = f;
    return (c.u + 0x8000u) >> 16;
}
static __device__ __forceinline__ uint32_t pk2(float a, float b) {
    union { float f; uint32_t u; } ca, cb; ca.f = a; cb.f = b;
    return ((ca.u + 0x8000u) >> 16) | ((cb.u + 0x8000u) & 0xffff0000u);
}

// ---------------- weight prep: frag-ready bf16, permuted k for L2/L3 -------
// frag-block = 64 lanes x 8 bf16: lane holds W[k][n], n-chunk per block.
// L1 ids: (ne*3+ks)*4+nt (ne=4 critic), 60 blocks; k identity; row 68 = b1.
// L2 ids: (ne*2+ks)*4+nt, 40 blocks; k permuted per sigma.
// L3 ids: ne*2+ks (experts N=16), 8..9 critic; k permuted per sigma.
__global__ void prep_kernel(const float* __restrict__ W1, const float* __restrict__ cW1,
                            const float* __restrict__ b1, const float* __restrict__ cb1,
                            const float* __restrict__ W2, const float* __restrict__ cW2,
                            const float* __restrict__ W3, const float* __restrict__ cW3,
                            short* __restrict__ wp) {
    int b = blockIdx.x, lane = threadIdx.x;
    int nl = lane & 15, quad = lane >> 4;
    short frag[8];
    if (b < 60) {
        int e = b / 12, rem = b % 12, ks = rem / 4, nt = rem % 4;
        int n = nt * 16 + nl;
#pragma unroll
        for (int j = 0; j < 8; j++) {
            int k = ks * 32 + quad * 8 + j;
            float v = 0.f;
            if (k < 68)       v = (e < 4) ? W1[(e * 68 + k) * 64 + n] : cW1[k * 64 + n];
            else if (k == 68) v = (e < 4) ? b1[e * 64 + n] : cb1[n];
            frag[j] = (short)rna_hi(v);
        }
    } else if (b < 100) {
        int u = b - 60, e = u / 8, ks = (u % 8) / 4, nt = u % 4;
        int n = nt * 16 + nl;
#pragma unroll
        for (int j = 0; j < 8; j++) {
            int ka = (2 * ks + (j >> 2)) * 16 + quad * 4 + (j & 3);  // sigma
            frag[j] = (short)rna_hi((e < 4) ? W2[(e * 64 + ka) * 64 + n] : cW2[ka * 64 + n]);
        }
    } else {
        int u = b - 100;
#pragma unroll
        for (int j = 0; j < 8; j++) {
            int ks = (u < 8) ? (u & 1) : (u - 8);
            int ka = (2 * ks + (j >> 2)) * 16 + quad * 4 + (j & 3);  // sigma
            float v;
            if (u < 8) { int ee = u >> 1; v = W3[(ee * 64 + ka) * 16 + nl]; }
            else       { v = (nl == 0) ? cW3[ka] : 0.f; }
            frag[j] = (short)rna_hi(v);
        }
    }
    v8s pk = { frag[0], frag[1], frag[2], frag[3], frag[4], frag[5], frag[6], frag[7] };
    *(v8s*)(wp + (size_t)b * 512 + lane * 8) = pk;
}

// ---------------- main kernel: wave = 32 tokens, all 5 nets, LDS-free ------

__global__ __launch_bounds__(256) void main_kernel(
    const float* __restrict__ obs, const float* __restrict__ gp,
    const int* __restrict__ hete, const short* __restrict__ wp,
    const float* __restrict__ b2, const float* __restrict__ b3,
    const float* __restrict__ cb2, const float* __restrict__ cb3,
    float* __restrict__ out)
{
    int tid = threadIdx.x, wv = tid >> 6, lane = tid & 63;
    int ml = lane & 15, quad = lane >> 4;
    int base = (blockIdx.x * 4 + wv) * 32;

    v8s xf[2][2];   // x B-frags k 0..63, [ks][tt], resident across all 5 nets
    v8s xg[2];      // k 64..95 frag: gp (quad0 j0..3) + bias-one (quad0 j4)
    int tpv[2];

#pragma unroll
    for (int tt = 0; tt < 2; tt++) {
        int tok = base + tt * 16 + ml;
        tpv[tt] = hete[tok];
        const float* xr = obs + (size_t)tok * 64 + quad * 8;
#pragma unroll
        for (int ks = 0; ks < 2; ks++) {
            float4 a = *(const float4*)(xr + ks * 32);
            float4 c = *(const float4*)(xr + ks * 32 + 4);
            union { uint32_t u[4]; v8s s; } cv;
            cv.u[0] = pk2(a.x, a.y); cv.u[1] = pk2(a.z, a.w);
            cv.u[2] = pk2(c.x, c.y); cv.u[3] = pk2(c.z, c.w);
            xf[ks][tt] = cv.s;
        }
        union { uint32_t u[4]; v8s s; } cg;
        if (quad == 0) {
            float4 g = *(const float4*)(gp + (size_t)(base >> 7) * 4);
            cg.u[0] = pk2(g.x, g.y); cg.u[1] = pk2(g.z, g.w);
            cg.u[2] = 0x00003F80u;  // k=68 : bf16(1.0) -> bias row of W1
            cg.u[3] = 0;
        } else { cg.u[0] = 0; cg.u[1] = 0; cg.u[2] = 0; cg.u[3] = 0; }
        xg[tt] = cg.s;
    }

    float cb3v = cb3[0];
    float oL[2][4];
    float oV[2];
#pragma unroll
    for (int tt = 0; tt < 2; tt++) {
        oL[tt][0] = 0.f; oL[tt][1] = 0.f; oL[tt][2] = 0.f; oL[tt][3] = 0.f;
        oV[tt] = 0.f;
    }

    for (int ne = 0; ne < 5; ne++) {   // 0..3 experts, 4 = critic
        // ---- layer 1: acc[tt][nt][reg] = h1[nt*16+quad*4+reg][tok=ml] ----
        v4f acc[2][4];
#pragma unroll
        for (int tt = 0; tt < 2; tt++)
#pragma unroll
            for (int nt = 0; nt < 4; nt++) acc[tt][nt] = (v4f){0.f, 0.f, 0.f, 0.f};
#pragma unroll
        for (int ks = 0; ks < 3; ks++) {
            v8s wa[4];
#pragma unroll
            for (int nt = 0; nt < 4; nt++)
                wa[nt] = *(const v8s*)(wp + (size_t)((ne * 3 + ks) * 4 + nt) * 512 + lane * 8);
#pragma unroll
            for (int tt = 0; tt < 2; tt++) {
                v8s xb = (ks < 2) ? xf[ks][tt] : xg[tt];
#pragma unroll
                for (int nt = 0; nt < 4; nt++)
                    acc[tt][nt] = __builtin_amdgcn_mfma_f32_16x16x32_bf16(wa[nt], xb, acc[tt][nt], 0, 0, 0);
            }
        }
        // ---- L2/L3 weights for this net ----
        v8s wa2[2][4];
#pragma unroll
        for (int ks2 = 0; ks2 < 2; ks2++)
#pragma unroll
            for (int nt = 0; nt < 4; nt++)
                wa2[ks2][nt] = *(const v8s*)(wp + WP2_OFF +
                    (size_t)((ne * 2 + ks2) * 4 + nt) * 512 + lane * 8);
        v8s w3f[2];
#pragma unroll
        for (int ks2 = 0; ks2 < 2; ks2++)
            w3f[ks2] = *(const v8s*)(wp + WP3_OFF +
                (size_t)((ne < 4) ? (ne * 2 + ks2) : (8 + ks2)) * 512 + lane * 8);
        const float* B2 = (ne < 4) ? (b2 + ne * 64) : cb2;

#pragma unroll
        for (int tt = 0; tt < 2; tt++) {
            // ---- pack h1 -> L2 B-frags, pure in-lane (sigma layout) ----
            v8s hf[2];
#pragma unroll
            for (int ks2 = 0; ks2 < 2; ks2++) {
                union { uint32_t u[4]; v8s s; } cv;
                cv.u[0] = pk2(fmaxf(acc[tt][2 * ks2][0], 0.f),     fmaxf(acc[tt][2 * ks2][1], 0.f));
                cv.u[1] = pk2(fmaxf(acc[tt][2 * ks2][2], 0.f),     fmaxf(acc[tt][2 * ks2][3], 0.f));
                cv.u[2] = pk2(fmaxf(acc[tt][2 * ks2 + 1][0], 0.f), fmaxf(acc[tt][2 * ks2 + 1][1], 0.f));
                cv.u[3] = pk2(fmaxf(acc[tt][2 * ks2 + 1][2], 0.f), fmaxf(acc[tt][2 * ks2 + 1][3], 0.f));
                hf[ks2] = cv.s;
            }
            // ---- layer 2, bias via acc-init ----
            v4f a2[4];
#pragma unroll
            for (int nt = 0; nt < 4; nt++)
                a2[nt] = *(const v4f*)(B2 + nt * 16 + quad * 4);
#pragma unroll
            for (int ks2 = 0; ks2 < 2; ks2++)
#pragma unroll
                for (int nt = 0; nt < 4; nt++)
                    a2[nt] = __builtin_amdgcn_mfma_f32_16x16x32_bf16(wa2[ks2][nt], hf[ks2], a2[nt], 0, 0, 0);
            // ---- pack h2 -> L3 B-frags ----
            v8s hf2[2];
#pragma unroll
            for (int ks2 = 0; ks2 < 2; ks2++) {
                union { uint32_t u[4]; v8s s; } cv;
                cv.u[0] = pk2(fmaxf(a2[2 * ks2][0], 0.f),     fmaxf(a2[2 * ks2][1], 0.f));
                cv.u[1] = pk2(fmaxf(a2[2 * ks2][2], 0.f),     fmaxf(a2[2 * ks2][3], 0.f));
                cv.u[2] = pk2(fmaxf(a2[2 * ks2 + 1][0], 0.f), fmaxf(a2[2 * ks2 + 1][1], 0.f));
                cv.u[3] = pk2(fmaxf(a2[2 * ks2 + 1][2], 0.f), fmaxf(a2[2 * ks2 + 1][3], 0.f));
                hf2[ks2] = cv.s;
            }
            // ---- layer 3, bias via acc-init (experts) ----
            v4f a3;
            if (ne < 4) a3 = *(const v4f*)(b3 + ne * 16 + quad * 4);
            else        a3 = (v4f){0.f, 0.f, 0.f, 0.f};
#pragma unroll
            for (int ks2 = 0; ks2 < 2; ks2++)
                a3 = __builtin_amdgcn_mfma_f32_16x16x32_bf16(w3f[ks2], hf2[ks2], a3, 0, 0, 0);

            if (ne < 4) {
#pragma unroll
                for (int rr = 0; rr < 4; rr++)
                    oL[tt][rr] = (tpv[tt] == ne) ? a3[rr] : oL[tt][rr];
            } else {
                oV[tt] = a3[0] + cb3v;   // valid on quad==0 (row 0)
            }
        }
    }

    // ---- store: lane (quad,ml) owns logits quad*4..+3 of token ml ----
#pragma unroll
    for (int tt = 0; tt < 2; tt++) {
        int tok = base + tt * 16 + ml;
        size_t o = (size_t)tok * 17 + quad * 4;
        out[o + 0] = oL[tt][0];
        out[o + 1] = oL[tt][1];
        out[o + 2] = oL[tt][2];
        out[o + 3] = oL[tt][3];
        if (quad == 0) out[(size_t)tok * 17 + 16] = oV[tt];
    }
}

// ---------------------------------------------------------------------------

extern "C" void kernel_launch(void* const* d_in, const int* in_sizes, int n_in,
                              void* d_out, int out_size, void* d_ws, size_t ws_size,
                              hipStream_t stream) {
    const float* obs = (const float*)d_in[0];
    const int*  hete = (const int*)d_in[1];
    const float* gp  = (const float*)d_in[2];
    const float* W1  = (const float*)d_in[3];
    const float* b1  = (const float*)d_in[4];
    const float* W2  = (const float*)d_in[5];
    const float* b2  = (const float*)d_in[6];
    const float* W3  = (const float*)d_in[7];
    const float* b3  = (const float*)d_in[8];
    const float* cW1 = (const float*)d_in[9];
    const float* cb1 = (const float*)d_in[10];
    const float* cW2 = (const float*)d_in[11];
    const float* cb2 = (const float*)d_in[12];
    const float* cW3 = (const float*)d_in[13];
    const float* cb3 = (const float*)d_in[14];
    float* out = (float*)d_out;

    short* wp = (short*)d_ws;   // 56320 shorts

    prep_kernel<<<110,   64, 0, stream>>>(W1, cW1, b1, cb1, W2, cW2, W3, cW3, wp);
    main_kernel<<<2048, 256, 0, stream>>>(obs, gp, hete, wp,
                                          b2, b3, cb2, cb3, out);
}